// Round 16
// baseline (1278.407 us; speedup 1.0000x reference)
//
#include <hip/hip_runtime.h>
#include <hip/hip_bf16.h>

// Problem constants
#define B_   2048   // batch
#define E_   512    // embedding / hidden
#define S_   64     // sequence length
#define K_   1024   // fused GEMM K = E (x part) + E (h part)
#define NG   2048   // 4*E gate rows

#define BM 128
#define BN 128
#define BK 64
#define ND  4         // LDS ring depth (prefetch distance 3)

typedef __attribute__((ext_vector_type(8))) short  bfrag8;
typedef __attribute__((ext_vector_type(4))) float  f32x4;

#define WAITVM(N) asm volatile("s_waitcnt vmcnt(" #N ")" ::: "memory")
#define SBAR() do { __builtin_amdgcn_s_barrier(); __builtin_amdgcn_sched_barrier(0); } while (0)

__device__ __forceinline__ void gload16(const void* g, void* l) {
  __builtin_amdgcn_global_load_lds(
      (const __attribute__((address_space(1))) unsigned int*)g,
      (__attribute__((address_space(3))) unsigned int*)l,
      16, 0, 0);
}

__device__ __forceinline__ float sigm(float x)      { return 1.f / (1.f + __expf(-x)); }
__device__ __forceinline__ float tanh_fast(float x) { return 2.f / (1.f + __expf(-2.f * x)) - 1.f; }

// Gate-interleaved permutation (verified rounds 1-15).
// Permuted row p: te = p>>7, c = p&127 = hi*64 + g*16 + q
//   e = te*32 + hi*16 + q ; original gate row n = g*512 + e
__global__ __launch_bounds__(256) void prep_weights(
    const float* __restrict__ Wih, const float* __restrict__ Whh,
    const float* __restrict__ bih, const float* __restrict__ bhh,
    __hip_bfloat16* __restrict__ Wp, float* __restrict__ biasP)
{
  int p  = blockIdx.x;
  int te = p >> 7;
  int c  = p & 127;
  int hi = (c >> 6) & 1;
  int g  = (c >> 4) & 3;
  int q  = c & 15;
  int e  = te * 32 + hi * 16 + q;
  int n  = g * E_ + e;
  const float* s0 = Wih + (size_t)n * E_;
  const float* s1 = Whh + (size_t)n * E_;
  __hip_bfloat16* dst = Wp + (size_t)p * K_;
  for (int k = threadIdx.x; k < E_; k += 256) {
    dst[k]       = __float2bfloat16(s0[k]);
    dst[E_ + k]  = __float2bfloat16(s1[k]);
  }
  if (threadIdx.x == 0) biasP[p] = bih[n] + bhh[n];
}

// Xe[t][b][e] = bf16(emb[x[b][t]][e])  -- one-time gather (verified r6/r9)
__global__ __launch_bounds__(256) void pregather(
    const int* __restrict__ x, const float* __restrict__ emb,
    __hip_bfloat16* __restrict__ Xe)
{
  int row  = blockIdx.x * 4 + (threadIdx.x >> 6);   // row = b*64 + t
  int lane = threadIdx.x & 63;
  int b = row >> 6, t = row & 63;
  size_t xi = (size_t)x[row];
  const float* src = emb + xi * E_ + lane * 8;
  float4 f0 = *(const float4*)(src);
  float4 f1 = *(const float4*)(src + 4);
  union { __hip_bfloat16 h[8]; uint4 v; } u;
  u.h[0] = __float2bfloat16(f0.x); u.h[1] = __float2bfloat16(f0.y);
  u.h[2] = __float2bfloat16(f0.z); u.h[3] = __float2bfloat16(f0.w);
  u.h[4] = __float2bfloat16(f1.x); u.h[5] = __float2bfloat16(f1.y);
  u.h[6] = __float2bfloat16(f1.z); u.h[7] = __float2bfloat16(f1.w);
  *(uint4*)(Xe + ((size_t)t * B_ + b) * E_ + lane * 8) = u.v;
}

// One fused LSTM timestep. 8 waves/block (2 waves/SIMD), 128x128 tile, BK=64,
// ND=4 ring, distance 3, counted vmcnt. A = [Xe[t] | Hprev] staged per-tile.
// Prologue = tiles only; bias+c issued at iter 8 (hide under MFMA).
// 16B-chunk involution swizzle (verified 0-conflict): cl = ch ^ ((ch>>3)&7).
__global__ __launch_bounds__(512, 1) void lstm_step(
    const __hip_bfloat16* __restrict__ Xe,     // [64][2048][512]
    const __hip_bfloat16* __restrict__ Hp,     // [2048][512] bf16
    __hip_bfloat16* __restrict__ Hn,           // [2048][512] bf16
    const __hip_bfloat16* __restrict__ Wp,     // [2048][1024] bf16 (permuted)
    const float* __restrict__ biasP,           // [2048] permuted
    float* __restrict__ c,                     // [2048][512] fp32
    float* __restrict__ out,                   // [2048][512] fp32
    int t)
{
  __shared__ __hip_bfloat16 As[ND][BM * BK];   // 4 x 16 KB
  __shared__ __hip_bfloat16 Bs[ND][BN * BK];   // 4 x 16 KB  (128 KB total)

  const int tid = threadIdx.x;
  // 256 blocks = 16 tm x 16 te; XCD-chunked: per XCD 8 tm x 4 te
  const int x7 = blockIdx.x & 7;
  const int i  = blockIdx.x >> 3;              // 0..31
  const int tm = (x7 & 1) * 8 + (i & 7);       // 0..15
  const int te = (x7 >> 1) * 4 + (i >> 3);     // 0..15

  const int w  = tid >> 6, l = tid & 63;
  const int wr = w >> 1;                       // 0..3: 32-row band
  const int wc = w & 1;                        // 0..1: 64-col half
  const int lq = l & 15, lh = l >> 4;

  const int arow0 = tm * BM;
  const int brow0 = te * BN;
  const int e     = te * 32 + wc * 16 + lq;

  // staging: 1024 chunks of 16B per tile; dest linear (gload_lds rule),
  // source = involution-swizzled chunk (row = cl>>3, k-chunk = cl&7)
  auto stageA = [&](int tt, int buf) {
#pragma unroll
    for (int it = 0; it < 2; ++it) {
      int ch  = it * 512 + tid;                // 0..1023
      int cl  = ch ^ ((ch >> 3) & 7);
      int row = cl >> 3, gr = cl & 7;
      const __hip_bfloat16* src = (tt < 8)
        ? Xe + ((size_t)t * B_ + arow0 + row) * E_ + tt * 64 + gr * 8
        : Hp + (size_t)(arow0 + row) * E_ + (tt - 8) * 64 + gr * 8;
      gload16(src, &As[buf][ch * 8]);
    }
  };
  auto stageB = [&](int tt, int buf) {
    const int k0 = tt * BK;
#pragma unroll
    for (int it = 0; it < 2; ++it) {
      int ch  = it * 512 + tid;
      int cl  = ch ^ ((ch >> 3) & 7);
      int row = cl >> 3, gr = cl & 7;
      gload16(Wp + (size_t)(brow0 + row) * K_ + k0 + gr * 8, &Bs[buf][ch * 8]);
    }
  };

  // ---- prologue: ONLY tiles 0..2 (4 loads/thread each; queue = 12) ----
  stageA(0, 0); stageB(0, 0);
  stageA(1, 1); stageB(1, 1);
  stageA(2, 2); stageB(2, 2);
  __builtin_amdgcn_sched_barrier(0);

  // ---- fragment offsets (swizzled reads) ----
  int aoff[2][2], boff[2][4];
#pragma unroll
  for (int ks = 0; ks < 2; ++ks) {
#pragma unroll
    for (int m = 0; m < 2; ++m) {
      int cl = (wr * 32 + m * 16 + lq) * 8 + ks * 4 + lh;
      aoff[ks][m] = (cl ^ ((cl >> 3) & 7)) * 8;
    }
#pragma unroll
    for (int n = 0; n < 4; ++n) {
      int cl = (wc * 64 + n * 16 + lq) * 8 + ks * 4 + lh;
      boff[ks][n] = (cl ^ ((cl >> 3) & 7)) * 8;
    }
  }

  f32x4 acc[2][4];
#pragma unroll
  for (int m = 0; m < 2; ++m)
#pragma unroll
    for (int n = 0; n < 4; ++n)
      acc[m][n] = (f32x4){0.f, 0.f, 0.f, 0.f};

  auto mfma_iter = [&](int rb) {
    const __hip_bfloat16* Ab = &As[rb][0];
    const __hip_bfloat16* Bb = &Bs[rb][0];
#pragma unroll
    for (int ks = 0; ks < 2; ++ks) {
      bfrag8 af[2], bfr[4];
#pragma unroll
      for (int m = 0; m < 2; ++m) af[m]  = *(const bfrag8*)(Ab + aoff[ks][m]);
#pragma unroll
      for (int n = 0; n < 4; ++n) bfr[n] = *(const bfrag8*)(Bb + boff[ks][n]);
      __builtin_amdgcn_s_setprio(1);
#pragma unroll
      for (int m = 0; m < 2; ++m)
#pragma unroll
        for (int n = 0; n < 4; ++n)
          acc[m][n] = __builtin_amdgcn_mfma_f32_16x16x32_bf16(af[m], bfr[n], acc[m][n], 0, 0, 0);
      __builtin_amdgcn_s_setprio(0);
    }
  };

  float bg[4];
  float cold[2][4];

  // ---- counted-vmcnt pipeline, 16 iters, distance 3 ----
  // ledger (per thread, 4 loads/tile):
  //  iters 0..7 : entry queue [t_kt,t_kt+1,t_kt+2]=12 -> WAITVM(8); stage t_kt+3
  //  iter 8     : + misc (bias 4 + c 8 = 12 loads) after stage -> queue 24
  //  iters 9..11: WAITVM(20) (drain t_kt only); stage
  //  iter 12    : WAITVM(8) (drains misc + t12); stage t15 -> 12
  //  iters 13..15: WAITVM(8/4/0)
#pragma unroll 1
  for (int kt = 0; kt < 8; ++kt) {
    WAITVM(8); SBAR();
    stageA(kt + 3, (kt + 3) & 3); stageB(kt + 3, (kt + 3) & 3);
    mfma_iter(kt & 3);
  }
  // iter 8
  WAITVM(8); SBAR();
  stageA(11, 3); stageB(11, 3);
#pragma unroll
  for (int n = 0; n < 4; ++n)
    bg[n] = biasP[te * 128 + wc * 64 + n * 16 + lq];
#pragma unroll
  for (int m = 0; m < 2; ++m)
#pragma unroll
    for (int r = 0; r < 4; ++r)
      cold[m][r] = c[(size_t)(arow0 + wr * 32 + m * 16 + lh * 4 + r) * E_ + e];
  __builtin_amdgcn_sched_barrier(0);
  mfma_iter(0);
  // iters 9..11
  WAITVM(20); SBAR(); stageA(12, 0); stageB(12, 0); mfma_iter(1);
  WAITVM(20); SBAR(); stageA(13, 1); stageB(13, 1); mfma_iter(2);
  WAITVM(20); SBAR(); stageA(14, 2); stageB(14, 2); mfma_iter(3);
  // iter 12 (drains misc + t12)
  WAITVM(8);  SBAR(); stageA(15, 3); stageB(15, 3); mfma_iter(0);
  // tail
  WAITVM(8);  SBAR(); mfma_iter(1);
  WAITVM(4);  SBAR(); mfma_iter(2);
  WAITVM(0);  SBAR(); mfma_iter(3);

  // ---- register epilogue ----
  const bool last = (t == S_ - 1);
#pragma unroll
  for (int m = 0; m < 2; ++m) {
#pragma unroll
    for (int r = 0; r < 4; ++r) {
      int b = arow0 + wr * 32 + m * 16 + lh * 4 + r;
      float iv = acc[m][0][r] + bg[0];
      float fv = acc[m][1][r] + bg[1];
      float gv = acc[m][2][r] + bg[2];
      float ov = acc[m][3][r] + bg[3];
      size_t cidx = (size_t)b * E_ + e;
      float ig = sigm(iv), fg = sigm(fv), gg = tanh_fast(gv), og = sigm(ov);
      float cn = fg * cold[m][r] + ig * gg;
      c[cidx] = cn;
      float h = og * tanh_fast(cn);
      if (last) out[cidx] = h;
      else      Hn[cidx]  = __float2bfloat16(h);
    }
  }
}

extern "C" void kernel_launch(void* const* d_in, const int* in_sizes, int n_in,
                              void* d_out, int out_size, void* d_ws, size_t ws_size,
                              hipStream_t stream) {
  const int*   x   = (const int*)d_in[0];
  const float* emb = (const float*)d_in[1];
  const float* Wih = (const float*)d_in[2];
  const float* Whh = (const float*)d_in[3];
  const float* bih = (const float*)d_in[4];
  const float* bhh = (const float*)d_in[5];
  float* out = (float*)d_out;
  (void)in_sizes; (void)n_in; (void)out_size; (void)ws_size;

  char* p = (char*)d_ws;
  __hip_bfloat16* Wp    = (__hip_bfloat16*)p;  p += (size_t)NG * K_ * 2;        // 4 MB
  float*          biasP = (float*)p;           p += (size_t)NG * 4;             // 8 KB
  __hip_bfloat16* Xe    = (__hip_bfloat16*)p;  p += (size_t)S_ * B_ * E_ * 2;   // 128 MB
  __hip_bfloat16* H0    = (__hip_bfloat16*)p;  p += (size_t)B_ * E_ * 2;        // 2 MB
  __hip_bfloat16* H1    = (__hip_bfloat16*)p;  p += (size_t)B_ * E_ * 2;        // 2 MB
  float*          c     = (float*)p;           p += (size_t)B_ * E_ * 4;        // 4 MB

  prep_weights<<<NG, 256, 0, stream>>>(Wih, Whh, bih, bhh, Wp, biasP);
  pregather<<<(B_ * S_) / 4, 256, 0, stream>>>(x, emb, Xe);
  hipMemsetAsync(H0, 0, (size_t)B_ * E_ * 2, stream);
  hipMemsetAsync(c,  0, (size_t)B_ * E_ * 4, stream);
  for (int t = 0; t < S_; ++t) {
    const __hip_bfloat16* Hprev = (t & 1) ? H1 : H0;
    __hip_bfloat16*       Hnext = (t & 1) ? H0 : H1;
    lstm_step<<<256, 512, 0, stream>>>(Xe, Hprev, Hnext, Wp, biasP, c, out, t);
  }
}

// Round 17
// 1066.338 us; speedup vs baseline: 1.1989x; 1.1989x over previous
//
#include <hip/hip_runtime.h>
#include <hip/hip_bf16.h>

// Problem constants
#define B_   2048   // batch
#define E_   512    // embedding / hidden
#define S_   64     // sequence length
#define K_   1024   // fused GEMM K = E (x part) + E (h part)
#define NG   2048   // 4*E gate rows

#define BM 128
#define BN 128
#define BK 128      // 8 K-iterations (iteration-count is the empirical cost law)

typedef __attribute__((ext_vector_type(8))) short  bfrag8;
typedef __attribute__((ext_vector_type(4))) float  f32x4;

#define WAITVM(N) asm volatile("s_waitcnt vmcnt(" #N ")" ::: "memory")
#define SBAR() do { __builtin_amdgcn_s_barrier(); __builtin_amdgcn_sched_barrier(0); } while (0)

__device__ __forceinline__ void gload16(const void* g, void* l) {
  __builtin_amdgcn_global_load_lds(
      (const __attribute__((address_space(1))) unsigned int*)g,
      (__attribute__((address_space(3))) unsigned int*)l,
      16, 0, 0);
}

__device__ __forceinline__ float sigm(float x)      { return 1.f / (1.f + __expf(-x)); }
__device__ __forceinline__ float tanh_fast(float x) { return 2.f / (1.f + __expf(-2.f * x)) - 1.f; }

// Gate-interleaved permutation (verified rounds 1-16).
// Permuted row p: te = p>>7, c = p&127 = hi*64 + g*16 + q
//   e = te*32 + hi*16 + q ; original gate row n = g*512 + e
__global__ __launch_bounds__(256) void prep_weights(
    const float* __restrict__ Wih, const float* __restrict__ Whh,
    const float* __restrict__ bih, const float* __restrict__ bhh,
    __hip_bfloat16* __restrict__ Wp, float* __restrict__ biasP)
{
  int p  = blockIdx.x;
  int te = p >> 7;
  int c  = p & 127;
  int hi = (c >> 6) & 1;
  int g  = (c >> 4) & 3;
  int q  = c & 15;
  int e  = te * 32 + hi * 16 + q;
  int n  = g * E_ + e;
  const float* s0 = Wih + (size_t)n * E_;
  const float* s1 = Whh + (size_t)n * E_;
  __hip_bfloat16* dst = Wp + (size_t)p * K_;
  for (int k = threadIdx.x; k < E_; k += 256) {
    dst[k]       = __float2bfloat16(s0[k]);
    dst[E_ + k]  = __float2bfloat16(s1[k]);
  }
  if (threadIdx.x == 0) biasP[p] = bih[n] + bhh[n];
}

// c = 0; A0[b][0:512] = bf16(emb[x[b][0]]); A0[b][512:1024] = 0 (h0 = 0)
__global__ __launch_bounds__(256) void init_state(
    const int* __restrict__ x, const float* __restrict__ emb,
    float* __restrict__ c, __hip_bfloat16* __restrict__ A0)
{
  int b  = blockIdx.x;
  int xi = x[(size_t)b * S_ + 0];
  const float* e = emb + (size_t)xi * E_;
  __hip_bfloat16* a = A0 + (size_t)b * K_;
  float* cr = c + (size_t)b * E_;
  for (int k = threadIdx.x; k < E_; k += 256) {
    a[k]       = __float2bfloat16(e[k]);
    a[E_ + k]  = __float2bfloat16(0.f);
    cr[k]      = 0.f;
  }
}

// One fused LSTM timestep. 8 waves (2/SIMD), 128x128 tile, BK=128:
// 8 K-iterations, ND=2 double-buffer, two-barrier loop, counted vmcnt.
// 16B-chunk involution swizzle for 16-chunk rows: cl = ch ^ ((ch>>4)&15).
__global__ __launch_bounds__(512, 1) void lstm_step(
    const __hip_bfloat16* __restrict__ Acur,   // [2048][1024] bf16
    __hip_bfloat16* __restrict__ Anext,        // [2048][1024] bf16
    const __hip_bfloat16* __restrict__ Wp,     // [2048][1024] bf16 (permuted)
    const float* __restrict__ biasP,           // [2048] permuted
    float* __restrict__ c,                     // [2048][512] fp32
    const int* __restrict__ x,                 // [2048][64] int32
    const float* __restrict__ emb,             // [32000][512] fp32
    float* __restrict__ out,                   // [2048][512] fp32
    int t)
{
  __shared__ __hip_bfloat16 As[2][BM * BK];    // 2 x 32 KB
  __shared__ __hip_bfloat16 Bs[2][BN * BK];    // 2 x 32 KB (128 KB total)

  const int tid = threadIdx.x;
  // 256 blocks = 16 tm x 16 te; XCD-chunked: per XCD 8 tm x 4 te
  const int x7 = blockIdx.x & 7;
  const int i  = blockIdx.x >> 3;              // 0..31
  const int tm = (x7 & 1) * 8 + (i & 7);       // 0..15
  const int te = (x7 >> 1) * 4 + (i >> 3);     // 0..15

  const int w  = tid >> 6, l = tid & 63;
  const int wr = w >> 1;                       // 0..3: 32-row band
  const int wc = w & 1;                        // 0..1: 64-col half
  const int lq = l & 15, lh = l >> 4;

  const int arow0 = tm * BM;
  const int brow0 = te * BN;
  const int e     = te * 32 + wc * 16 + lq;

  // ---- prologue loads: bias(4), cold c(8), next-step indices(8) = 20 ----
  float bg[4];
#pragma unroll
  for (int n = 0; n < 4; ++n)
    bg[n] = biasP[te * 128 + wc * 64 + n * 16 + lq];

  float cold[2][4];
  int   xiv[2][4];
  const int tn = (t < S_ - 1) ? t + 1 : S_ - 1;
#pragma unroll
  for (int m = 0; m < 2; ++m)
#pragma unroll
    for (int r = 0; r < 4; ++r) {
      int b = arow0 + wr * 32 + m * 16 + lh * 4 + r;
      cold[m][r] = c[(size_t)b * E_ + e];
      xiv[m][r]  = x[(size_t)b * S_ + tn];
    }
  __builtin_amdgcn_sched_barrier(0);

  // staging: 2048 chunks of 16B per tile; dest linear (gload_lds rule),
  // source = involution-swizzled chunk (row = cl>>4, k-chunk = cl&15)
  auto stageA = [&](int kt, int buf) {
    const int k0 = kt * BK;
#pragma unroll
    for (int it = 0; it < 4; ++it) {
      int ch  = it * 512 + tid;                // 0..2047
      int cl  = ch ^ ((ch >> 4) & 15);
      int row = cl >> 4, gr = cl & 15;
      gload16(Acur + (size_t)(arow0 + row) * K_ + k0 + gr * 8, &As[buf][ch * 8]);
    }
  };
  auto stageB = [&](int kt, int buf) {
    const int k0 = kt * BK;
#pragma unroll
    for (int it = 0; it < 4; ++it) {
      int ch  = it * 512 + tid;
      int cl  = ch ^ ((ch >> 4) & 15);
      int row = cl >> 4, gr = cl & 15;
      gload16(Wp + (size_t)(brow0 + row) * K_ + k0 + gr * 8, &Bs[buf][ch * 8]);
    }
  };

  // tile 0
  stageA(0, 0); stageB(0, 0);
  __builtin_amdgcn_sched_barrier(0);

  // emb gather for t+1 (8 loads; compiler's xiv wait drains misc, leaves t0)
  float ev[2][4];
#pragma unroll
  for (int m = 0; m < 2; ++m)
#pragma unroll
    for (int r = 0; r < 4; ++r)
      ev[m][r] = emb[(size_t)xiv[m][r] * E_ + e];
  __builtin_amdgcn_sched_barrier(0);

  // tile 1
  stageA(1, 1); stageB(1, 1);
  __builtin_amdgcn_sched_barrier(0);

  // ---- fragment offsets (swizzled reads; uniform 32 B/bank per wave-read) ----
  int aoff[4][2], boff[4][4];
#pragma unroll
  for (int ks = 0; ks < 4; ++ks) {
#pragma unroll
    for (int m = 0; m < 2; ++m) {
      int cl = (wr * 32 + m * 16 + lq) * 16 + ks * 4 + lh;
      aoff[ks][m] = (cl ^ ((cl >> 4) & 15)) * 8;
    }
#pragma unroll
    for (int n = 0; n < 4; ++n) {
      int cl = (wc * 64 + n * 16 + lq) * 16 + ks * 4 + lh;
      boff[ks][n] = (cl ^ ((cl >> 4) & 15)) * 8;
    }
  }

  f32x4 acc[2][4];
#pragma unroll
  for (int m = 0; m < 2; ++m)
#pragma unroll
    for (int n = 0; n < 4; ++n)
      acc[m][n] = (f32x4){0.f, 0.f, 0.f, 0.f};

  auto mfma_iter = [&](int rb) {
    const __hip_bfloat16* Ab = &As[rb][0];
    const __hip_bfloat16* Bb = &Bs[rb][0];
#pragma unroll
    for (int ks = 0; ks < 4; ++ks) {
      bfrag8 af[2], bfr[4];
#pragma unroll
      for (int m = 0; m < 2; ++m) af[m]  = *(const bfrag8*)(Ab + aoff[ks][m]);
#pragma unroll
      for (int n = 0; n < 4; ++n) bfr[n] = *(const bfrag8*)(Bb + boff[ks][n]);
      __builtin_amdgcn_s_setprio(1);
#pragma unroll
      for (int m = 0; m < 2; ++m)
#pragma unroll
        for (int n = 0; n < 4; ++n)
          acc[m][n] = __builtin_amdgcn_mfma_f32_16x16x32_bf16(af[m], bfr[n], acc[m][n], 0, 0, 0);
      __builtin_amdgcn_s_setprio(0);
    }
  };

  // ---- two-barrier loop, 8 iters; 8 loads/thread/tile ----
  // entry outstanding: [t0(<=8 after xiv-gate), ev(8), t1(8)]
  // iter kt: WAITVM(8) -> tile kt done (leaves tile kt+1's 8);
  //          SBAR; MFMA(buf kt&1); SBAR; stage t(kt+2) into buf kt&1.
  WAITVM(8); SBAR(); mfma_iter(0); SBAR(); stageA(2, 0); stageB(2, 0);
  WAITVM(8); SBAR(); mfma_iter(1); SBAR(); stageA(3, 1); stageB(3, 1);
  WAITVM(8); SBAR(); mfma_iter(0); SBAR(); stageA(4, 0); stageB(4, 0);
  WAITVM(8); SBAR(); mfma_iter(1); SBAR(); stageA(5, 1); stageB(5, 1);
  WAITVM(8); SBAR(); mfma_iter(0); SBAR(); stageA(6, 0); stageB(6, 0);
  WAITVM(8); SBAR(); mfma_iter(1); SBAR(); stageA(7, 1); stageB(7, 1);
  WAITVM(8); SBAR(); mfma_iter(0);
  WAITVM(0); SBAR(); mfma_iter(1);

  // ---- register epilogue ----
  const bool last = (t == S_ - 1);
#pragma unroll
  for (int m = 0; m < 2; ++m) {
#pragma unroll
    for (int r = 0; r < 4; ++r) {
      int b = arow0 + wr * 32 + m * 16 + lh * 4 + r;
      float iv = acc[m][0][r] + bg[0];
      float fv = acc[m][1][r] + bg[1];
      float gv = acc[m][2][r] + bg[2];
      float ov = acc[m][3][r] + bg[3];
      size_t cidx = (size_t)b * E_ + e;
      float ig = sigm(iv), fg = sigm(fv), gg = tanh_fast(gv), og = sigm(ov);
      float cn = fg * cold[m][r] + ig * gg;
      c[cidx] = cn;
      float h = og * tanh_fast(cn);
      if (last) {
        out[cidx] = h;
      } else {
        Anext[(size_t)b * K_ + E_ + e] = __float2bfloat16(h);
        Anext[(size_t)b * K_ + e]      = __float2bfloat16(ev[m][r]);
      }
    }
  }
}

extern "C" void kernel_launch(void* const* d_in, const int* in_sizes, int n_in,
                              void* d_out, int out_size, void* d_ws, size_t ws_size,
                              hipStream_t stream) {
  const int*   x   = (const int*)d_in[0];
  const float* emb = (const float*)d_in[1];
  const float* Wih = (const float*)d_in[2];
  const float* Whh = (const float*)d_in[3];
  const float* bih = (const float*)d_in[4];
  const float* bhh = (const float*)d_in[5];
  float* out = (float*)d_out;
  (void)in_sizes; (void)n_in; (void)out_size; (void)ws_size;

  char* p = (char*)d_ws;
  __hip_bfloat16* Wp    = (__hip_bfloat16*)p;  p += (size_t)NG * K_ * 2;  // 4 MB
  float*          biasP = (float*)p;           p += (size_t)NG * 4;       // 8 KB
  float*          c     = (float*)p;           p += (size_t)B_ * E_ * 4;  // 4 MB
  __hip_bfloat16* A0    = (__hip_bfloat16*)p;  p += (size_t)B_ * K_ * 2;  // 4 MB
  __hip_bfloat16* A1    = (__hip_bfloat16*)p;  p += (size_t)B_ * K_ * 2;  // 4 MB

  prep_weights<<<NG, 256, 0, stream>>>(Wih, Whh, bih, bhh, Wp, biasP);
  init_state<<<B_, 256, 0, stream>>>(x, emb, c, A0);
  for (int t = 0; t < S_; ++t) {
    __hip_bfloat16* Ac = (t & 1) ? A1 : A0;
    __hip_bfloat16* An = (t & 1) ? A0 : A1;
    lstm_step<<<256, 512, 0, stream>>>(Ac, An, Wp, biasP, c, x, emb, out, t);
  }
}